// Round 16
// baseline (55.826 us; speedup 1.0000x reference)
//
#include <hip/hip_runtime.h>
#include <math.h>

#define BB 2
#define LL 5
#define NN 10
#define CC 64
#define HH 128
#define WW 256
#define PP (HH*WW)          // 32768
#define NP (NN*PP)          // 327680

// ---------------- ws float layout (R10's, proven) ----------------
// [0..127]      gate (B*C)
// [128..1407]   cntp (1280 per-block mask-count partials)
// [2048..67583]       partS [1024][64]
// [67584..133119]     partM [1024][64]
// [139264 .. 139264+NP)  mask

// fused conf+gaussian+threshold stencil: one block per (agent n, row h).
__global__ __launch_bounds__(256) void k_confmask(const float* __restrict__ psm,
                                                  const float* __restrict__ inv_delay,
                                                  const float* __restrict__ ewc_w,
                                                  const float* __restrict__ ewc_b,
                                                  float* __restrict__ mask,
                                                  float* __restrict__ cntp) {
    const float g0 = 0.15915494309189535f;
    const float g1 = 0.09653235263005391f;
    const float g2 = 0.05854983152431917f;
    const float g4 = 0.02153927930184936f;
    const float g5 = 0.01306423328468446f;
    const float g8 = 0.00291502449738744f;
    const float G[25] = { g8,g5,g4,g5,g8,
                          g5,g2,g1,g2,g5,
                          g4,g1,g0,g1,g4,
                          g5,g2,g1,g2,g5,
                          g8,g5,g4,g5,g8 };
    int blk = blockIdx.x;           // 0..1279
    int n   = blk >> 7;             // agent
    int h   = blk & 127;            // row
    int t   = threadIdx.x;          // col
    float enc = tanhf(inv_delay[n] * ewc_w[0] + ewc_b[0]) + 1.0f;
    const float* pn0 = psm + (n * 2 + 0) * PP;
    const float* pn1 = psm + (n * 2 + 1) * PP;

    __shared__ float cs[5][WW];
#pragma unroll
    for (int r = 0; r < 5; ++r) {
        int row = h - 2 + r;
        float v = 0.0f;
        if ((unsigned)row < (unsigned)HH) {
            float a0 = pn0[row * WW + t];
            float a1 = pn1[row * WW + t];
            v = fmaxf(1.0f / (1.0f + expf(-a0)), 1.0f / (1.0f + expf(-a1))) * enc;
        }
        cs[r][t] = v;
    }
    __syncthreads();

    float acc = 0.0f;
#pragma unroll
    for (int r = 0; r < 5; ++r) {
#pragma unroll
        for (int dx = -2; dx <= 2; ++dx) {
            int col = t + dx;
            if ((unsigned)col < (unsigned)WW)
                acc += cs[r][col] * G[r * 5 + (dx + 2)];
        }
    }
    float mv = (acc > 0.01f) ? 1.0f : 0.0f;
    if ((n % LL) == 0) mv = 1.0f;             // ego always communicates
    mask[n * PP + h * WW + t] = mv;

    float v = mv;
#pragma unroll
    for (int o = 32; o > 0; o >>= 1) v += __shfl_down(v, o, 64);
    __shared__ float sred[4];
    int lane = t & 63, wid = t >> 6;
    if (lane == 0) sred[wid] = v;
    __syncthreads();
    if (t == 0) cntp[blk] = sred[0] + sred[1] + sred[2] + sred[3];
}

// scores + softmax + fuse (R9-exact core) + LDS-staged per-block stats.
// Stats via fstat[64][65] (padded: conflict-free writes AND chunked reads,
// 2 lanes/bank = free per m136) instead of R10's 96-shfl tree (+6us there).
// No min-waves (R6), no atomics (R5), scalar loads (R12/R13: float2 spills).
__global__ __launch_bounds__(512) void k_attnfuse(const float* __restrict__ x,
                                                  const float* __restrict__ mask,
                                                  const float* __restrict__ inv_delay,
                                                  const float* __restrict__ ew_w,
                                                  const float* __restrict__ ew_b,
                                                  float* __restrict__ out,
                                                  float* __restrict__ partS,
                                                  float* __restrict__ partM) {
    int blk = blockIdx.x;
    int b   = blk >> 9;                 // 512 blocks per batch
    int tid  = threadIdx.x;
    int lane = tid & 63;
    int wv   = tid >> 6;                // 0..7
    int p = ((blk & 511) << 6) + lane;
    const float* xb = x + b * (LL * CC * PP) + p;
    int cbase = wv << 3;                // 8 channels per wave

    float xr[8][5];
    float s5[5] = {0.f, 0.f, 0.f, 0.f, 0.f};
#pragma unroll
    for (int cc = 0; cc < 8; ++cc) {
        const float* xc = xb + (cbase + cc) * PP;
#pragma unroll
        for (int l = 0; l < LL; ++l) xr[cc][l] = xc[l * CC * PP];
        float q = xr[cc][0];
#pragma unroll
        for (int l = 0; l < LL; ++l) s5[l] += q * xr[cc][l];
    }

    __shared__ float sred[8][5][64];     // 10 KB
#pragma unroll
    for (int l = 0; l < LL; ++l) sred[wv][l][lane] = s5[l];
    __syncthreads();

    // all waves redundantly finish the softmax
    float ew0 = ew_w[0], eb0 = ew_b[0];
    float a[5];
    {
        float m[5], t[5], sc[5], e[5];
#pragma unroll
        for (int l = 0; l < LL; ++l) {
            float tl = 0.f;
#pragma unroll
            for (int w = 0; w < 8; ++w) tl += sred[w][l][lane];
            t[l] = tl;
            float en = tanhf(inv_delay[b * LL + l] * ew0 + eb0) + 1.0f;
            m[l] = en * mask[(b * LL + l) * PP + p];
        }
        const float scale = 0.125f;               // 1/sqrt(64)
#pragma unroll
        for (int l = 0; l < LL; ++l) sc[l] = t[l] * m[0] * m[l] * scale;
        float mxv = fmaxf(fmaxf(fmaxf(sc[0], sc[1]), fmaxf(sc[2], sc[3])), sc[4]);
        float sum = 0.f;
#pragma unroll
        for (int l = 0; l < LL; ++l) { e[l] = expf(sc[l] - mxv); sum += e[l]; }
        float inv = 1.0f / sum;
#pragma unroll
        for (int l = 0; l < LL; ++l) a[l] = e[l] * inv * m[l];
    }

    __shared__ float fstat[CC][65];      // 16.6 KB, padded stride 65
    float* ob = out + b * (CC * PP) + p;
#pragma unroll
    for (int cc = 0; cc < 8; ++cc) {
        float f = 0.f;
#pragma unroll
        for (int l = 0; l < LL; ++l) f += a[l] * xr[cc][l];
        ob[(cbase + cc) * PP] = f;
        fstat[cbase + cc][lane] = f;
    }
    __syncthreads();

    // per-block channel stats: thread t reduces channel c = t>>3, pixels
    // [seg*8, seg*8+8); combine 8 segment-partials via width-8 shfl.
    {
        int c   = tid >> 3;
        int seg = tid & 7;
        const float* row = &fstat[c][seg * 8];
        float s = row[0], m = row[0];
#pragma unroll
        for (int j = 1; j < 8; ++j) {
            s += row[j];
            m = fmaxf(m, row[j]);
        }
#pragma unroll
        for (int o = 4; o > 0; o >>= 1) {
            s += __shfl_down(s, o, 8);
            m = fmaxf(m, __shfl_down(m, o, 8));
        }
        if (seg == 0) {
            partS[blk * CC + c] = s;
            partM[blk * CC + c] = m;
        }
    }
}

// single block: reduce partials -> gate[B*C] and comm_rate (R10-proven)
__global__ __launch_bounds__(256) void k_finish(const float* __restrict__ partS,
                                                const float* __restrict__ partM,
                                                const float* __restrict__ cntp,
                                                const float* __restrict__ w1,
                                                const float* __restrict__ w2,
                                                float* __restrict__ gate,
                                                float* __restrict__ comm_out) {
    int t = threadIdx.x;
    int pair = t >> 1;          // (b,c) 0..127
    int sub  = t & 1;
    __shared__ float sS[2][128], sM[2][128];
    {
        int b = pair >> 6, c = pair & 63;
        float s = 0.f, m = -INFINITY;
        int base = b * 512 + sub * 256;
        for (int pb = 0; pb < 256; ++pb) {
            int i = (base + pb) * CC + c;
            s += partS[i];
            m = fmaxf(m, partM[i]);
        }
        sS[sub][pair] = s;
        sM[sub][pair] = m;
    }
    __syncthreads();
    __shared__ float stA[128], stM[128];
    if (t < 128) {
        stA[t] = (sS[0][t] + sS[1][t]) * (1.0f / (float)PP);
        stM[t] = fmaxf(sM[0][t], sM[1][t]);
    }
    __syncthreads();
    __shared__ float hs[BB][4];
    if (t < BB * 4) {
        int b = t >> 2, j = t & 3;
        float ha = 0.f, hm = 0.f;
        for (int c = 0; c < CC; ++c) {
            float wv = w1[j * CC + c];
            ha += stA[b * CC + c] * wv;
            hm += stM[b * CC + c] * wv;
        }
        hs[b][j] = fmaxf(ha, 0.0f) + fmaxf(hm, 0.0f);
    }
    __syncthreads();
    if (t < 128) {
        int b = t >> 6, c = t & 63;
        float g = hs[b][0] * w2[c * 4 + 0] + hs[b][1] * w2[c * 4 + 1]
                + hs[b][2] * w2[c * 4 + 2] + hs[b][3] * w2[c * 4 + 3];
        gate[t] = 1.0f / (1.0f + expf(-g));
    }
    // comm_rate from 1280 confmask partials
    float s = 0.f;
    for (int j = t; j < 1280; j += 256) s += cntp[j];
#pragma unroll
    for (int o = 32; o > 0; o >>= 1) s += __shfl_down(s, o, 64);
    __shared__ float cred[4];
    if ((t & 63) == 0) cred[t >> 6] = s;
    __syncthreads();
    if (t == 0)
        comm_out[0] = (cred[0] + cred[1] + cred[2] + cred[3]) * (1.0f / (float)NP);
}

// pure scale: out *= gate[b,c]
__global__ __launch_bounds__(256) void k_scale(float* __restrict__ out,
                                               const float* __restrict__ gate) {
    int idx = blockIdx.x * 256 + threadIdx.x;   // < B*C*PP/4
    int bc = idx >> 13;                         // PP/4 = 8192
    float g = gate[bc];
    float4 v = ((float4*)out)[idx];
    v.x *= g; v.y *= g; v.z *= g; v.w *= g;
    ((float4*)out)[idx] = v;
}

extern "C" void kernel_launch(void* const* d_in, const int* in_sizes, int n_in,
                              void* d_out, int out_size, void* d_ws, size_t ws_size,
                              hipStream_t stream) {
    const float* x         = (const float*)d_in[0];
    const float* psm       = (const float*)d_in[1];
    const float* inv_delay = (const float*)d_in[2];
    const float* ew_w      = (const float*)d_in[3];
    const float* ew_b      = (const float*)d_in[4];
    const float* ewc_w     = (const float*)d_in[5];
    const float* ewc_b     = (const float*)d_in[6];
    const float* w1        = (const float*)d_in[7];
    const float* w2        = (const float*)d_in[8];
    float* out = (float*)d_out;
    float* wsf = (float*)d_ws;

    float* gate  = wsf;
    float* cntp  = wsf + 128;
    float* partS = wsf + 2048;
    float* partM = wsf + 2048 + 1024 * CC;
    float* mask  = wsf + 139264;

    k_confmask<<<NN * HH, 256, 0, stream>>>(psm, inv_delay, ewc_w, ewc_b, mask, cntp);
    k_attnfuse<<<1024, 512, 0, stream>>>(x, mask, inv_delay, ew_w, ew_b, out, partS, partM);
    k_finish<<<1, 256, 0, stream>>>(partS, partM, cntp, w1, w2, gate, out + BB * CC * PP);
    k_scale<<<BB * CC * PP / 4 / 256, 256, 0, stream>>>(out, gate);
}